// Round 12
// baseline (270.859 us; speedup 1.0000x reference)
//
#include <hip/hip_runtime.h>
#include <math.h>

constexpr int N_ = 65536;
constexpr int D_ = 64;
constexpr int M_ = 4096;
constexpr int Q_ = 4;              // M split into 4 quarters (blockIdx.y)
constexpr int TQ = M_ / Q_ / 16;   // 64 tiles per quarter
constexpr int GT = 2;              // tiles per staged LDS group (4 KB)
constexpr int NG = TQ / GT;        // 32 groups per quarter

typedef __attribute__((ext_vector_type(8))) short  short8;  // 8 x bf16
typedef __attribute__((ext_vector_type(4))) float  f32x4;

__device__ inline unsigned long long pack_dl(float d, unsigned m) {
    return ((unsigned long long)__float_as_uint(d) << 32) | m;
}
__device__ inline unsigned short f2bf(float x) {  // RNE f32 -> bf16 bits
    union { float f; unsigned u; } v; v.f = x;
    return (unsigned short)((v.u + 0x7fffu + ((v.u >> 16) & 1u)) >> 16);
}
__device__ inline unsigned umin32(unsigned a, unsigned b) { return a < b ? a : b; }
__device__ inline unsigned umax32(unsigned a, unsigned b) { return a > b ? a : b; }

// ---------------- prep: bf16 casts + fragment-tiled C + (-0.5*c_sq) ----------------
// ChiT: tile t, ks, g4, col, e -> ushort off t*1024 + ks*512 + g4*128 + col*8 + e
__global__ __launch_bounds__(256) void pwd_prep(
        const float* __restrict__ p, const float* __restrict__ c,
        const float* __restrict__ c_sq,
        unsigned short* __restrict__ Phi, unsigned short* __restrict__ ChiT,
        float* __restrict__ nhcsq) {
    const int tid = blockIdx.x * 256 + threadIdx.x;
    constexpr int PT = N_ * D_ / 8;
    constexpr int CT = M_ * D_ / 8;
    if (tid < PT) {
        const float4* src = reinterpret_cast<const float4*>(p) + (size_t)tid * 2;
        float4 x = src[0], y = src[1];
        unsigned short o[8] = {f2bf(x.x), f2bf(x.y), f2bf(x.z), f2bf(x.w),
                               f2bf(y.x), f2bf(y.y), f2bf(y.z), f2bf(y.w)};
        *reinterpret_cast<short8*>(Phi + (size_t)tid * 8) = *reinterpret_cast<short8*>(o);
    } else if (tid < PT + CT) {
        const int id  = tid - PT;
        const int col = id & 15;
        const int g4  = (id >> 4) & 3;
        const int ks  = (id >> 6) & 1;
        const int t   = id >> 7;
        const float* src = c + (size_t)(t * 16 + col) * D_ + ks * 32 + g4 * 8;
        float4 x = *reinterpret_cast<const float4*>(src);
        float4 y = *reinterpret_cast<const float4*>(src + 4);
        unsigned short o[8] = {f2bf(x.x), f2bf(x.y), f2bf(x.z), f2bf(x.w),
                               f2bf(y.x), f2bf(y.y), f2bf(y.z), f2bf(y.w)};
        *reinterpret_cast<short8*>(ChiT + (size_t)id * 8) = *reinterpret_cast<short8*>(o);
    } else if (tid < PT + CT + M_) {
        const int m = tid - PT - CT;
        nhcsq[m] = -0.5f * c_sq[m];
    }
}

// ---------------- pass A: LDS-pipelined MFMA scan, packed-key top-2 ----------------
// mfma(A=centroid fragment, B=point fragment): D row=(lane>>4)*4+reg = centroid,
// col=lane&15 = point [validated rounds 3/5/7/8, absmax 0.0]. acc = dot - csq/2.
// keyf = (pn/2 + 1) - acc = dist/2 + 1 > 0  (bias const per tracker -> order kept).
// key  = (bits(keyf) & ~0xFFF) | label  -> u32 min == (min dist, then min label).
__global__ __launch_bounds__(256, 8) void pwd_scan(
        const unsigned short* __restrict__ Phi,
        const float* __restrict__ pn,
        const unsigned short* __restrict__ ChiT,
        const float* __restrict__ nhcsq,
        unsigned short* __restrict__ cand) {
    __shared__ __align__(16) char  lds_chi[2][GT * 2048];  // 2 x 4 KB
    __shared__ __align__(16) float nh_lds[1024];           // 4 KB (this quarter)

    const int tid  = threadIdx.x;
    const int lane = tid & 63;
    const int wav  = tid >> 6;
    const int col  = lane & 15;
    const int g4   = lane >> 4;
    const int quarter = blockIdx.y;
    const int pbase   = blockIdx.x * 128 + wav * 32;

    // stage -0.5*c_sq (this quarter) into LDS: 256 threads x 1 float4
    reinterpret_cast<float4*>(nh_lds)[tid] =
        reinterpret_cast<const float4*>(nhcsq + quarter * 1024)[tid];

    // point fragments (B operand) in registers
    short8 bfr[2][2];
#pragma unroll
    for (int g = 0; g < 2; ++g)
#pragma unroll
        for (int ks = 0; ks < 2; ++ks)
            bfr[g][ks] = *reinterpret_cast<const short8*>(
                Phi + (size_t)(pbase + g * 16 + col) * D_ + ks * 32 + g4 * 8);

    float pn2[2];
#pragma unroll
    for (int g = 0; g < 2; ++g)
        pn2[g] = 0.5f * pn[pbase + g * 16 + col] + 1.0f;

    // packed-key top-2 trackers per (g, r-pair)
    unsigned k0[2][2], k1[2][2];
#pragma unroll
    for (int g = 0; g < 2; ++g)
#pragma unroll
        for (int tr = 0; tr < 2; ++tr) { k0[g][tr] = 0xFFFFFFFFu; k1[g][tr] = 0xFFFFFFFFu; }

    const char* gchi = reinterpret_cast<const char*>(ChiT) + (size_t)quarter * TQ * 2048;

#define STAGE_LOAD(R, grp) \
    R = *reinterpret_cast<const float4*>(gchi + (size_t)(grp) * (GT * 2048) + tid * 16);

#define STAGE_WRITE(BUF, R) \
    *reinterpret_cast<float4*>(lds_chi[BUF] + tid * 16) = R;

#define COMPUTE_GROUP(BUF, grp)                                                  \
    _Pragma("unroll")                                                            \
    for (int t = 0; t < GT; ++t) {                                               \
        const char* tb = lds_chi[BUF] + t * 2048;                                \
        const short8 a0 = *reinterpret_cast<const short8*>(tb + g4*256 + col*16);\
        const short8 a1 = *reinterpret_cast<const short8*>(tb + 1024 + g4*256 + col*16); \
        const int tg = (grp) * GT + t;                                           \
        const float4 q = *reinterpret_cast<const float4*>(nh_lds + tg*16 + g4*4);\
        const unsigned mb = (unsigned)(quarter * 1024 + tg * 16 + g4 * 4);       \
        _Pragma("unroll")                                                        \
        for (int g = 0; g < 2; ++g) {                                            \
            f32x4 acc = {q.x, q.y, q.z, q.w};                                    \
            acc = __builtin_amdgcn_mfma_f32_16x16x32_bf16(a0, bfr[g][0], acc, 0, 0, 0); \
            acc = __builtin_amdgcn_mfma_f32_16x16x32_bf16(a1, bfr[g][1], acc, 0, 0, 0); \
            _Pragma("unroll")                                                    \
            for (int r = 0; r < 4; ++r) {                                        \
                const int tr = r >> 1;                                           \
                const float keyf = pn2[g] - acc[r];            /* dist/2 + 1 */  \
                const unsigned key = (__float_as_uint(keyf) & 0xFFFFF000u)       \
                                     | (mb + r);               /* v_and_or */    \
                const unsigned t0 = k0[g][tr];                                   \
                k0[g][tr] = umin32(t0, key);                                     \
                k1[g][tr] = umin32(k1[g][tr], umax32(t0, key));                  \
            }                                                                    \
        }                                                                        \
    }

    float4 rA, rB;
    STAGE_LOAD(rA, 0)
    __syncthreads();  // nh_lds ready

#pragma unroll 1
    for (int gp = 0; gp < NG; gp += 2) {
        STAGE_WRITE(0, rA)
        __syncthreads();
        STAGE_LOAD(rB, gp + 1)             // prefetch under compute
        COMPUTE_GROUP(0, gp)

        STAGE_WRITE(1, rB)
        __syncthreads();
        if (gp + 2 < NG) { STAGE_LOAD(rA, gp + 2) }
        COMPUTE_GROUP(1, gp + 1)
    }

    // labels live in key low 12 bits; 4 u16 per (lane, g): cand[(q*N+pt)*16 + g4*4]
#pragma unroll
    for (int g = 0; g < 2; ++g) {
        const int pt = pbase + g * 16 + col;
        uint2 w;
        w.x = (k0[g][0] & 0xFFFu) | ((k1[g][0] & 0xFFFu) << 16);
        w.y = (k0[g][1] & 0xFFFu) | ((k1[g][1] & 0xFFFu) << 16);
        *reinterpret_cast<uint2*>(
            cand + ((size_t)(quarter * N_ + pt) * 16 + g4 * 4)) = w;
    }
#undef STAGE_LOAD
#undef STAGE_WRITE
#undef COMPUTE_GROUP
}

// ---------------- pass B: exact f32 re-eval, 8 threads/point x 8 candidates --------
// Round-8 postmortem: 2 thr/pt = 512 blocks = 2 waves/SIMD -> latency-bound (VALUBusy
// 7.7%). 8 thr/pt = 2048 blocks ~ 8 blocks/CU -> TLP hides the candidate-row latency.
__global__ __launch_bounds__(256) void pwd_exact(
        const float* __restrict__ p, const float* __restrict__ pn,
        const float* __restrict__ c, const float* __restrict__ c_sq,
        const unsigned short* __restrict__ cand, float* __restrict__ out) {
    const int t  = blockIdx.x * 256 + threadIdx.x;
    const int pt = t >> 3, j = t & 7;

    float pr[D_];
    const float4* p4 = reinterpret_cast<const float4*>(p + (size_t)pt * D_);
#pragma unroll
    for (int i = 0; i < D_ / 4; ++i) {
        float4 v = p4[i];
        pr[4*i+0] = v.x; pr[4*i+1] = v.y; pr[4*i+2] = v.z; pr[4*i+3] = v.w;
    }
    const float pnn = pn[pt];

    // this thread's 8 labels: quarter j>>1, half (j&1) of its 16 u16 slots
    const uint4 w = *reinterpret_cast<const uint4*>(
        cand + (size_t)((j >> 1) * N_ + pt) * 16 + (j & 1) * 8);
    const unsigned ww[4] = {w.x, w.y, w.z, w.w};

    unsigned long long best = ~0ull;
#pragma unroll
    for (int idx = 0; idx < 8; ++idx) {
        const unsigned m = (ww[idx >> 1] >> ((idx & 1) * 16)) & 0xffffu;
        const float* cm = c + (size_t)m * D_;
        float a0 = 0.f, a1 = 0.f, a2 = 0.f, a3 = 0.f;
#pragma unroll
        for (int k = 0; k < D_; k += 4) {   // round-2 canonical arithmetic
            a0 = fmaf(pr[k+0], cm[k+0], a0);
            a1 = fmaf(pr[k+1], cm[k+1], a1);
            a2 = fmaf(pr[k+2], cm[k+2], a2);
            a3 = fmaf(pr[k+3], cm[k+3], a3);
        }
        const float dot  = (a0 + a1) + (a2 + a3);
        const float dist = fmaf(-2.f, dot, pnn + c_sq[m]);
        const unsigned long long key = pack_dl(dist, m);
        best = key < best ? key : best;
    }
    unsigned long long o1 = __shfl_xor(best, 1); best = o1 < best ? o1 : best;
    unsigned long long o2 = __shfl_xor(best, 2); best = o2 < best ? o2 : best;
    unsigned long long o4 = __shfl_xor(best, 4); best = o4 < best ? o4 : best;
    if (j == 0) {
        out[pt]      = __uint_as_float((unsigned)(best >> 32));
        out[N_ + pt] = (float)(unsigned)(best & 0xffffffffu);
    }
}

// ---------------- fallback: f32 VALU path ------------------------------------------
constexpr int FCH = 8;
constexpr int FMC = M_ / FCH;

__global__ __launch_bounds__(256) void pwd_chunk(
        const float* __restrict__ p, const float* __restrict__ pn,
        const float* __restrict__ c, const float* __restrict__ c_sq,
        unsigned long long* __restrict__ ws) {
    const int n = blockIdx.x * 256 + threadIdx.x;
    const int mbase = blockIdx.y * FMC;
    float prr[D_];
    const float4* p4 = reinterpret_cast<const float4*>(p + (size_t)n * D_);
#pragma unroll
    for (int i = 0; i < D_ / 4; ++i) {
        float4 v = p4[i];
        prr[4*i+0] = v.x; prr[4*i+1] = v.y; prr[4*i+2] = v.z; prr[4*i+3] = v.w;
    }
    const float pnn = pn[n];
    float bestD = INFINITY;
    int   bestM = mbase;
#pragma unroll 2
    for (int mi = 0; mi < FMC; ++mi) {
        const int m = mbase + mi;
        const float* cm = c + (size_t)m * D_;
        float a0 = 0.f, a1 = 0.f, a2 = 0.f, a3 = 0.f;
#pragma unroll
        for (int k = 0; k < D_; k += 4) {
            a0 = fmaf(prr[k+0], cm[k+0], a0);
            a1 = fmaf(prr[k+1], cm[k+1], a1);
            a2 = fmaf(prr[k+2], cm[k+2], a2);
            a3 = fmaf(prr[k+3], cm[k+3], a3);
        }
        const float dot  = (a0 + a1) + (a2 + a3);
        const float dist = fmaf(-2.f, dot, pnn + c_sq[m]);
        if (dist < bestD) { bestD = dist; bestM = m; }
    }
    atomicMin(&ws[n], pack_dl(bestD, (unsigned)bestM));
}

__global__ __launch_bounds__(256) void pwd_out(
        const unsigned long long* __restrict__ results, float* __restrict__ out) {
    const int n = blockIdx.x * 256 + threadIdx.x;
    const unsigned long long v = results[n];
    out[n]      = __uint_as_float((unsigned)(v >> 32));
    out[N_ + n] = (float)(unsigned)(v & 0xffffffffu);
}

extern "C" void kernel_launch(void* const* d_in, const int* in_sizes, int n_in,
                              void* d_out, int out_size, void* d_ws, size_t ws_size,
                              hipStream_t stream) {
    const float* p    = (const float*)d_in[0];
    const float* pn   = (const float*)d_in[1];
    const float* c    = (const float*)d_in[2];
    const float* c_sq = (const float*)d_in[3];
    float* out = (float*)d_out;

    char* ws = (char*)d_ws;
    const size_t off_phi  = 0;
    const size_t off_chi  = (size_t)N_ * D_ * 2;                 // 8 MB
    const size_t off_nhc  = off_chi + (size_t)M_ * D_ * 2;       // +512 KB
    const size_t off_cand = off_nhc + (size_t)M_ * 4;            // +16 KB
    const size_t need     = off_cand + (size_t)Q_ * N_ * 16 * 2; // +8 MB

    if (ws_size >= need) {
        unsigned short* Phi   = (unsigned short*)(ws + off_phi);
        unsigned short* ChiT  = (unsigned short*)(ws + off_chi);
        float*          nhcsq = (float*)(ws + off_nhc);
        unsigned short* cand  = (unsigned short*)(ws + off_cand);

        constexpr int PREP_T = N_ * D_ / 8 + M_ * D_ / 8 + M_;
        pwd_prep<<<(PREP_T + 255) / 256, 256, 0, stream>>>(p, c, c_sq, Phi, ChiT, nhcsq);
        dim3 sgrid(N_ / 128, Q_);
        pwd_scan<<<sgrid, 256, 0, stream>>>(Phi, pn, ChiT, nhcsq, cand);
        pwd_exact<<<(N_ * 8) / 256, 256, 0, stream>>>(p, pn, c, c_sq, cand, out);
    } else if (ws_size >= (size_t)N_ * 8) {
        unsigned long long* results = (unsigned long long*)ws;
        hipMemsetAsync(ws, 0xFF, (size_t)N_ * 8, stream);
        dim3 grid(N_ / 256, FCH);
        pwd_chunk<<<grid, 256, 0, stream>>>(p, pn, c, c_sq, results);
        pwd_out<<<N_ / 256, 256, 0, stream>>>(results, out);
    }
}

// Round 13
// 159.909 us; speedup vs baseline: 1.6938x; 1.6938x over previous
//
#include <hip/hip_runtime.h>
#include <math.h>

constexpr int N_ = 65536;
constexpr int D_ = 64;
constexpr int M_ = 4096;
constexpr int Q_ = 4;              // M split into 4 quarters (blockIdx.y)
constexpr int TQ = M_ / Q_ / 16;   // 64 tiles per quarter
constexpr int GT = 2;              // tiles per staged LDS group (4 KB)
constexpr int NG = TQ / GT;        // 32 groups per quarter

typedef __attribute__((ext_vector_type(8))) short  short8;  // 8 x bf16
typedef __attribute__((ext_vector_type(4))) float  f32x4;

__device__ inline unsigned long long pack_dl(float d, unsigned m) {
    return ((unsigned long long)__float_as_uint(d) << 32) | m;
}
__device__ inline unsigned short f2bf(float x) {  // RNE f32 -> bf16 bits
    union { float f; unsigned u; } v; v.f = x;
    return (unsigned short)((v.u + 0x7fffu + ((v.u >> 16) & 1u)) >> 16);
}
__device__ inline unsigned umin32(unsigned a, unsigned b) { return a < b ? a : b; }
__device__ inline unsigned umax32(unsigned a, unsigned b) { return a > b ? a : b; }

__device__ inline short8 load_bf8(const float* src) {  // 8 f32 -> 8 bf16 (RNE)
    float4 x = *reinterpret_cast<const float4*>(src);
    float4 y = *reinterpret_cast<const float4*>(src + 4);
    unsigned short o[8] = {f2bf(x.x), f2bf(x.y), f2bf(x.z), f2bf(x.w),
                           f2bf(y.x), f2bf(y.y), f2bf(y.z), f2bf(y.w)};
    return *reinterpret_cast<short8*>(o);
}

// ---------------- prep: fragment-tiled bf16 C + (-0.5*c_sq). (P cast on the fly.) --
// ChiT: tile t, ks, g4, col, e -> ushort off t*1024 + ks*512 + g4*128 + col*8 + e
__global__ __launch_bounds__(256) void pwd_prep(
        const float* __restrict__ c, const float* __restrict__ c_sq,
        unsigned short* __restrict__ ChiT, float* __restrict__ nhcsq) {
    const int tid = blockIdx.x * 256 + threadIdx.x;
    constexpr int CT = M_ * D_ / 8;   // 32768
    if (tid < CT) {
        const int id  = tid;               // id = ((t*2+ks)*4+g4)*16+col
        const int col = id & 15;
        const int g4  = (id >> 4) & 3;
        const int ks  = (id >> 6) & 1;
        const int t   = id >> 7;
        short8 v = load_bf8(c + (size_t)(t * 16 + col) * D_ + ks * 32 + g4 * 8);
        *reinterpret_cast<short8*>(ChiT + (size_t)id * 8) = v;
    } else if (tid < CT + M_) {
        const int m = tid - CT;
        nhcsq[m] = -0.5f * c_sq[m];
    }
}

// ---------------- pass A: LDS-pipelined MFMA scan, packed-key top-2 ----------------
// mfma(A=centroid fragment, B=point fragment): D row=(lane>>4)*4+reg = centroid,
// col=lane&15 = point [validated rounds 3/5/7/8/12, absmax 0.0]. acc = dot - csq/2.
// keyf = (pn/2 + 1) - acc = dist/2 + 1 > 0  (bias const per point -> order kept).
// key  = (bits(keyf) & ~0xFFF) | label  -> u32 min == (min dist, then min label).
// Round-12 change: write FULL 32-bit keys (quantized dist + label) so the exact pass
// can window-filter; P fragments cast from f32 on the fly (same RNE f2bf as before).
__global__ __launch_bounds__(256, 8) void pwd_scan(
        const float* __restrict__ p,
        const float* __restrict__ pn,
        const unsigned short* __restrict__ ChiT,
        const float* __restrict__ nhcsq,
        unsigned* __restrict__ candk) {
    __shared__ __align__(16) char  lds_chi[2][GT * 2048];  // 2 x 4 KB
    __shared__ __align__(16) float nh_lds[1024];           // 4 KB (this quarter)

    const int tid  = threadIdx.x;
    const int lane = tid & 63;
    const int wav  = tid >> 6;
    const int col  = lane & 15;
    const int g4   = lane >> 4;
    const int quarter = blockIdx.y;
    const int pbase   = blockIdx.x * 128 + wav * 32;

    // stage -0.5*c_sq (this quarter) into LDS: 256 threads x 1 float4
    reinterpret_cast<float4*>(nh_lds)[tid] =
        reinterpret_cast<const float4*>(nhcsq + quarter * 1024)[tid];

    // point fragments (B operand): f32 load + RNE cast, held in registers
    short8 bfr[2][2];
#pragma unroll
    for (int g = 0; g < 2; ++g)
#pragma unroll
        for (int ks = 0; ks < 2; ++ks)
            bfr[g][ks] = load_bf8(
                p + (size_t)(pbase + g * 16 + col) * D_ + ks * 32 + g4 * 8);

    float pn2[2];
#pragma unroll
    for (int g = 0; g < 2; ++g)
        pn2[g] = 0.5f * pn[pbase + g * 16 + col] + 1.0f;

    // packed-key top-2 trackers per (g, r-pair)
    unsigned k0[2][2], k1[2][2];
#pragma unroll
    for (int g = 0; g < 2; ++g)
#pragma unroll
        for (int tr = 0; tr < 2; ++tr) { k0[g][tr] = 0xFFFFFFFFu; k1[g][tr] = 0xFFFFFFFFu; }

    const char* gchi = reinterpret_cast<const char*>(ChiT) + (size_t)quarter * TQ * 2048;

#define STAGE_LOAD(R, grp) \
    R = *reinterpret_cast<const float4*>(gchi + (size_t)(grp) * (GT * 2048) + tid * 16);

#define STAGE_WRITE(BUF, R) \
    *reinterpret_cast<float4*>(lds_chi[BUF] + tid * 16) = R;

#define COMPUTE_GROUP(BUF, grp)                                                  \
    _Pragma("unroll")                                                            \
    for (int t = 0; t < GT; ++t) {                                               \
        const char* tb = lds_chi[BUF] + t * 2048;                                \
        const short8 a0 = *reinterpret_cast<const short8*>(tb + g4*256 + col*16);\
        const short8 a1 = *reinterpret_cast<const short8*>(tb + 1024 + g4*256 + col*16); \
        const int tg = (grp) * GT + t;                                           \
        const float4 q = *reinterpret_cast<const float4*>(nh_lds + tg*16 + g4*4);\
        const unsigned mb = (unsigned)(quarter * 1024 + tg * 16 + g4 * 4);       \
        _Pragma("unroll")                                                        \
        for (int g = 0; g < 2; ++g) {                                            \
            f32x4 acc = {q.x, q.y, q.z, q.w};                                    \
            acc = __builtin_amdgcn_mfma_f32_16x16x32_bf16(a0, bfr[g][0], acc, 0, 0, 0); \
            acc = __builtin_amdgcn_mfma_f32_16x16x32_bf16(a1, bfr[g][1], acc, 0, 0, 0); \
            _Pragma("unroll")                                                    \
            for (int r = 0; r < 4; ++r) {                                        \
                const int tr = r >> 1;                                           \
                const float keyf = pn2[g] - acc[r];            /* dist/2 + 1 */  \
                const unsigned key = (__float_as_uint(keyf) & 0xFFFFF000u)       \
                                     | (mb + r);               /* v_and_or */    \
                const unsigned t0 = k0[g][tr];                                   \
                k0[g][tr] = umin32(t0, key);                                     \
                k1[g][tr] = umin32(k1[g][tr], umax32(t0, key));                  \
            }                                                                    \
        }                                                                        \
    }

    float4 rA, rB;
    STAGE_LOAD(rA, 0)
    __syncthreads();  // nh_lds ready

#pragma unroll 1
    for (int gp = 0; gp < NG; gp += 2) {
        STAGE_WRITE(0, rA)
        __syncthreads();
        STAGE_LOAD(rB, gp + 1)             // prefetch under compute
        COMPUTE_GROUP(0, gp)

        STAGE_WRITE(1, rB)
        __syncthreads();
        if (gp + 2 < NG) { STAGE_LOAD(rA, gp + 2) }
        COMPUTE_GROUP(1, gp + 1)
    }

    // write 4 full keys per (lane, g): candk[(q*N+pt)*16 + g4*4 .. +3]
#pragma unroll
    for (int g = 0; g < 2; ++g) {
        const int pt = pbase + g * 16 + col;
        uint4 w;
        w.x = k0[g][0]; w.y = k1[g][0]; w.z = k0[g][1]; w.w = k1[g][1];
        *reinterpret_cast<uint4*>(
            candk + ((size_t)(quarter * N_ + pt) * 16 + g4 * 4)) = w;
    }
#undef STAGE_LOAD
#undef STAGE_WRITE
#undef COMPUTE_GROUP
}

// ---------------- pass B: window-filtered exact re-eval, 4 threads/point ------------
// Round-12 postmortem: evaluating all 64 candidate rows/point = 75M scattered L2
// transactions = transaction-bound (VALUBusy 5.5%). Fix: use the scan's quantized
// approx dists to evaluate ONLY candidates within min+1.5 (dist/2 scale; error bound
// |dist/2 err| <= Sum|p c| * 2^-8 ~ 0.31 worst-case, so margin is ~2x safe).
__global__ __launch_bounds__(256) void pwd_exact(
        const float* __restrict__ p, const float* __restrict__ pn,
        const float* __restrict__ c, const float* __restrict__ c_sq,
        const unsigned* __restrict__ candk, float* __restrict__ out) {
    const int t  = blockIdx.x * 256 + threadIdx.x;
    const int pt = t >> 2, q = t & 3;

    // my quarter's 16 keys (one 64B line)
    const uint4* kw = reinterpret_cast<const uint4*>(candk + ((size_t)q * N_ + pt) * 16);
    uint4 w0 = kw[0], w1 = kw[1], w2 = kw[2], w3 = kw[3];
    const unsigned ks[16] = {w0.x, w0.y, w0.z, w0.w, w1.x, w1.y, w1.z, w1.w,
                             w2.x, w2.y, w2.z, w2.w, w3.x, w3.y, w3.z, w3.w};
    unsigned mn = ks[0];
#pragma unroll
    for (int i = 1; i < 16; ++i) mn = umin32(mn, ks[i]);
    mn = umin32(mn, (unsigned)__shfl_xor((int)mn, 1));
    mn = umin32(mn, (unsigned)__shfl_xor((int)mn, 2));   // point-global min key
    const float thr = __uint_as_float(mn & 0xFFFFF000u) + 1.5f;

    bool any = false;
#pragma unroll
    for (int i = 0; i < 16; ++i)
        any |= (__uint_as_float(ks[i] & 0xFFFFF000u) <= thr);

    unsigned long long best = ~0ull;
    if (any) {                          // typically 1-2 lanes per point enter
        float pr[D_];
        const float4* p4 = reinterpret_cast<const float4*>(p + (size_t)pt * D_);
#pragma unroll
        for (int i = 0; i < D_ / 4; ++i) {
            float4 v = p4[i];
            pr[4*i+0] = v.x; pr[4*i+1] = v.y; pr[4*i+2] = v.z; pr[4*i+3] = v.w;
        }
        const float pnn = pn[pt];
#pragma unroll 1
        for (int i = 0; i < 16; ++i) {
            if (__uint_as_float(ks[i] & 0xFFFFF000u) > thr) continue;
            const unsigned m = ks[i] & 0xFFFu;
            const float* cm = c + (size_t)m * D_;
            float a0 = 0.f, a1 = 0.f, a2 = 0.f, a3 = 0.f;
#pragma unroll
            for (int k = 0; k < D_; k += 4) {   // round-2 canonical arithmetic
                a0 = fmaf(pr[k+0], cm[k+0], a0);
                a1 = fmaf(pr[k+1], cm[k+1], a1);
                a2 = fmaf(pr[k+2], cm[k+2], a2);
                a3 = fmaf(pr[k+3], cm[k+3], a3);
            }
            const float dot  = (a0 + a1) + (a2 + a3);
            const float dist = fmaf(-2.f, dot, pnn + c_sq[m]);
            const unsigned long long key = pack_dl(dist, m);
            best = key < best ? key : best;
        }
    }
    // merge across the point's 4 lanes; min-key lane always evaluated >=1 candidate
    unsigned long long o1 = __shfl_xor(best, 1); best = o1 < best ? o1 : best;
    unsigned long long o2 = __shfl_xor(best, 2); best = o2 < best ? o2 : best;
    if (q == 0) {
        out[pt]      = __uint_as_float((unsigned)(best >> 32));
        out[N_ + pt] = (float)(unsigned)(best & 0xffffffffu);
    }
}

// ---------------- fallback: f32 VALU path ------------------------------------------
constexpr int FCH = 8;
constexpr int FMC = M_ / FCH;

__global__ __launch_bounds__(256) void pwd_chunk(
        const float* __restrict__ p, const float* __restrict__ pn,
        const float* __restrict__ c, const float* __restrict__ c_sq,
        unsigned long long* __restrict__ ws) {
    const int n = blockIdx.x * 256 + threadIdx.x;
    const int mbase = blockIdx.y * FMC;
    float prr[D_];
    const float4* p4 = reinterpret_cast<const float4*>(p + (size_t)n * D_);
#pragma unroll
    for (int i = 0; i < D_ / 4; ++i) {
        float4 v = p4[i];
        prr[4*i+0] = v.x; prr[4*i+1] = v.y; prr[4*i+2] = v.z; prr[4*i+3] = v.w;
    }
    const float pnn = pn[n];
    float bestD = INFINITY;
    int   bestM = mbase;
#pragma unroll 2
    for (int mi = 0; mi < FMC; ++mi) {
        const int m = mbase + mi;
        const float* cm = c + (size_t)m * D_;
        float a0 = 0.f, a1 = 0.f, a2 = 0.f, a3 = 0.f;
#pragma unroll
        for (int k = 0; k < D_; k += 4) {
            a0 = fmaf(prr[k+0], cm[k+0], a0);
            a1 = fmaf(prr[k+1], cm[k+1], a1);
            a2 = fmaf(prr[k+2], cm[k+2], a2);
            a3 = fmaf(prr[k+3], cm[k+3], a3);
        }
        const float dot  = (a0 + a1) + (a2 + a3);
        const float dist = fmaf(-2.f, dot, pnn + c_sq[m]);
        if (dist < bestD) { bestD = dist; bestM = m; }
    }
    atomicMin(&ws[n], pack_dl(bestD, (unsigned)bestM));
}

__global__ __launch_bounds__(256) void pwd_out(
        const unsigned long long* __restrict__ results, float* __restrict__ out) {
    const int n = blockIdx.x * 256 + threadIdx.x;
    const unsigned long long v = results[n];
    out[n]      = __uint_as_float((unsigned)(v >> 32));
    out[N_ + n] = (float)(unsigned)(v & 0xffffffffu);
}

extern "C" void kernel_launch(void* const* d_in, const int* in_sizes, int n_in,
                              void* d_out, int out_size, void* d_ws, size_t ws_size,
                              hipStream_t stream) {
    const float* p    = (const float*)d_in[0];
    const float* pn   = (const float*)d_in[1];
    const float* c    = (const float*)d_in[2];
    const float* c_sq = (const float*)d_in[3];
    float* out = (float*)d_out;

    char* ws = (char*)d_ws;
    const size_t off_chi  = 0;                                   // 512 KB
    const size_t off_nhc  = (size_t)M_ * D_ * 2;                 // +16 KB
    const size_t off_cand = off_nhc + (size_t)M_ * 4;
    const size_t need     = off_cand + (size_t)Q_ * N_ * 16 * 4; // +16 MB

    if (ws_size >= need) {
        unsigned short* ChiT  = (unsigned short*)(ws + off_chi);
        float*          nhcsq = (float*)(ws + off_nhc);
        unsigned*       candk = (unsigned*)(ws + off_cand);

        constexpr int PREP_T = M_ * D_ / 8 + M_;
        pwd_prep<<<(PREP_T + 255) / 256, 256, 0, stream>>>(c, c_sq, ChiT, nhcsq);
        dim3 sgrid(N_ / 128, Q_);
        pwd_scan<<<sgrid, 256, 0, stream>>>(p, pn, ChiT, nhcsq, candk);
        pwd_exact<<<(N_ * 4) / 256, 256, 0, stream>>>(p, pn, c, c_sq, candk, out);
    } else if (ws_size >= (size_t)N_ * 8) {
        unsigned long long* results = (unsigned long long*)ws;
        hipMemsetAsync(ws, 0xFF, (size_t)N_ * 8, stream);
        dim3 grid(N_ / 256, FCH);
        pwd_chunk<<<grid, 256, 0, stream>>>(p, pn, c, c_sq, results);
        pwd_out<<<N_ / 256, 256, 0, stream>>>(results, out);
    }
}

// Round 14
// 154.041 us; speedup vs baseline: 1.7584x; 1.0381x over previous
//
#include <hip/hip_runtime.h>
#include <math.h>

constexpr int N_ = 65536;
constexpr int D_ = 64;
constexpr int M_ = 4096;
constexpr int Q_ = 4;              // M split into 4 quarters (blockIdx.y)
constexpr int TQ = M_ / Q_ / 16;   // 64 tiles per quarter

typedef __attribute__((ext_vector_type(8))) short  short8;  // 8 x bf16
typedef __attribute__((ext_vector_type(4))) float  f32x4;

__device__ inline unsigned long long pack_dl(float d, unsigned m) {
    return ((unsigned long long)__float_as_uint(d) << 32) | m;
}
__device__ inline unsigned short f2bf(float x) {  // RNE f32 -> bf16 bits
    union { float f; unsigned u; } v; v.f = x;
    return (unsigned short)((v.u + 0x7fffu + ((v.u >> 16) & 1u)) >> 16);
}
__device__ inline unsigned umin32(unsigned a, unsigned b) { return a < b ? a : b; }
__device__ inline unsigned umax32(unsigned a, unsigned b) { return a > b ? a : b; }

__device__ inline short8 load_bf8(const float* src) {  // 8 f32 -> 8 bf16 (RNE)
    float4 x = *reinterpret_cast<const float4*>(src);
    float4 y = *reinterpret_cast<const float4*>(src + 4);
    unsigned short o[8] = {f2bf(x.x), f2bf(x.y), f2bf(x.z), f2bf(x.w),
                           f2bf(y.x), f2bf(y.y), f2bf(y.z), f2bf(y.w)};
    return *reinterpret_cast<short8*>(o);
}

// ---------------- prep: fragment-tiled bf16 C + (-0.5*c_sq) -------------------------
// ChiT: tile t, ks, g4, col, e -> ushort off t*1024 + ks*512 + g4*128 + col*8 + e
__global__ __launch_bounds__(256) void pwd_prep(
        const float* __restrict__ c, const float* __restrict__ c_sq,
        unsigned short* __restrict__ ChiT, float* __restrict__ nhcsq) {
    const int tid = blockIdx.x * 256 + threadIdx.x;
    constexpr int CT = M_ * D_ / 8;   // 32768
    if (tid < CT) {
        const int id  = tid;               // id = ((t*2+ks)*4+g4)*16+col
        const int col = id & 15;
        const int g4  = (id >> 4) & 3;
        const int ks  = (id >> 6) & 1;
        const int t   = id >> 7;
        short8 v = load_bf8(c + (size_t)(t * 16 + col) * D_ + ks * 32 + g4 * 8);
        *reinterpret_cast<short8*>(ChiT + (size_t)id * 8) = v;
    } else if (tid < CT + M_) {
        const int m = tid - CT;
        nhcsq[m] = -0.5f * c_sq[m];
    }
}

// ---------------- pass A: barrier-free MFMA scan, packed-key top-2 -----------------
// Round-13 postmortem: LDS double-buffer cost 64 barrier-pairs/block; VALUBusy capped
// at 64%. Chi-quarter (128 KB) is L2-resident -> read fragments DIRECT from global
// (same b128 pattern, wave spans 4 KB contiguous = fully coalesced), no barriers, no
// staging VALU. Arithmetic path identical to validated rounds 3/5/7/8/12/13.
// mfma(A=centroid fragment, B=point fragment): D row=(lane>>4)*4+reg = centroid,
// col=lane&15 = point. acc = dot - csq/2. keyf = (pn/2+1) - acc = dist/2+1 > 0.
// key = (bits(keyf) & ~0xFFF) | label -> u32 min == (min dist, then min label).
__global__ __launch_bounds__(256, 8) void pwd_scan(
        const float* __restrict__ p,
        const float* __restrict__ pn,
        const unsigned short* __restrict__ ChiT,
        const float* __restrict__ nhcsq,
        unsigned* __restrict__ candk) {
    const int tid  = threadIdx.x;
    const int lane = tid & 63;
    const int col  = lane & 15;
    const int g4   = lane >> 4;
    const int quarter = blockIdx.y;
    const int pbase   = blockIdx.x * 128 + (tid >> 6) * 32;

    // point fragments (B operand): f32 load + RNE cast, held in registers
    short8 bfr[2][2];
#pragma unroll
    for (int g = 0; g < 2; ++g)
#pragma unroll
        for (int ks = 0; ks < 2; ++ks)
            bfr[g][ks] = load_bf8(
                p + (size_t)(pbase + g * 16 + col) * D_ + ks * 32 + g4 * 8);

    float pn2[2];
#pragma unroll
    for (int g = 0; g < 2; ++g)
        pn2[g] = 0.5f * pn[pbase + g * 16 + col] + 1.0f;

    // packed-key top-2 trackers per (g, r-pair)
    unsigned k0[2][2], k1[2][2];
#pragma unroll
    for (int g = 0; g < 2; ++g)
#pragma unroll
        for (int tr = 0; tr < 2; ++tr) { k0[g][tr] = 0xFFFFFFFFu; k1[g][tr] = 0xFFFFFFFFu; }

    const char*  gchi = reinterpret_cast<const char*>(ChiT) + (size_t)quarter * TQ * 2048;
    const float* nhq  = nhcsq + quarter * 1024;

#pragma unroll 2
    for (int t = 0; t < TQ; ++t) {
        const char* tb = gchi + (size_t)t * 2048;
        const short8 a0 = *reinterpret_cast<const short8*>(tb + g4 * 256 + col * 16);
        const short8 a1 = *reinterpret_cast<const short8*>(tb + 1024 + g4 * 256 + col * 16);
        const float4 q  = *reinterpret_cast<const float4*>(nhq + t * 16 + g4 * 4);
        const unsigned mb = (unsigned)(quarter * 1024 + t * 16 + g4 * 4);
#pragma unroll
        for (int g = 0; g < 2; ++g) {
            f32x4 acc = {q.x, q.y, q.z, q.w};
            acc = __builtin_amdgcn_mfma_f32_16x16x32_bf16(a0, bfr[g][0], acc, 0, 0, 0);
            acc = __builtin_amdgcn_mfma_f32_16x16x32_bf16(a1, bfr[g][1], acc, 0, 0, 0);
#pragma unroll
            for (int r = 0; r < 4; ++r) {
                const int tr = r >> 1;
                const float keyf = pn2[g] - acc[r];            // dist/2 + 1
                const unsigned key = (__float_as_uint(keyf) & 0xFFFFF000u)
                                     | (mb + r);               // v_and_or
                const unsigned t0 = k0[g][tr];
                k0[g][tr] = umin32(t0, key);
                k1[g][tr] = umin32(k1[g][tr], umax32(t0, key));
            }
        }
    }

    // write 4 full keys per (lane, g): candk[(q*N+pt)*16 + g4*4 .. +3]
#pragma unroll
    for (int g = 0; g < 2; ++g) {
        const int pt = pbase + g * 16 + col;
        uint4 w;
        w.x = k0[g][0]; w.y = k1[g][0]; w.z = k0[g][1]; w.w = k1[g][1];
        *reinterpret_cast<uint4*>(
            candk + ((size_t)(quarter * N_ + pt) * 16 + g4 * 4)) = w;
    }
}

// ---------------- pass B: window-filtered exact re-eval, ffs-masked loop ------------
// Round-13 postmortem: exec-masked full 16-slot loop serialized ~16 eval slots/wave
// though only ~1.5 candidates/point qualify. Fix: 16-bit qualify mask + ffs loop ->
// wave trip count = max per-lane popcount (~1-2). Key re-loaded by index from L1
// (avoids runtime-indexed register array -> scratch, rule #20).
__global__ __launch_bounds__(256) void pwd_exact(
        const float* __restrict__ p, const float* __restrict__ pn,
        const float* __restrict__ c, const float* __restrict__ c_sq,
        const unsigned* __restrict__ candk, float* __restrict__ out) {
    const int t  = blockIdx.x * 256 + threadIdx.x;
    const int pt = t >> 2, q = t & 3;

    // my quarter's 16 keys (one 64B line)
    const uint4* kw = reinterpret_cast<const uint4*>(candk + ((size_t)q * N_ + pt) * 16);
    uint4 w0 = kw[0], w1 = kw[1], w2 = kw[2], w3 = kw[3];
    const unsigned ks[16] = {w0.x, w0.y, w0.z, w0.w, w1.x, w1.y, w1.z, w1.w,
                             w2.x, w2.y, w2.z, w2.w, w3.x, w3.y, w3.z, w3.w};
    unsigned mn = ks[0];
#pragma unroll
    for (int i = 1; i < 16; ++i) mn = umin32(mn, ks[i]);
    mn = umin32(mn, (unsigned)__shfl_xor((int)mn, 1));
    mn = umin32(mn, (unsigned)__shfl_xor((int)mn, 2));   // point-global min key
    const float thr = __uint_as_float(mn & 0xFFFFF000u) + 1.5f;

    unsigned mask = 0;
#pragma unroll
    for (int i = 0; i < 16; ++i)
        mask |= (__uint_as_float(ks[i] & 0xFFFFF000u) <= thr) ? (1u << i) : 0u;

    unsigned long long best = ~0ull;
    if (mask) {                          // typically only the min-key lane
        float pr[D_];
        const float4* p4 = reinterpret_cast<const float4*>(p + (size_t)pt * D_);
#pragma unroll
        for (int i = 0; i < D_ / 4; ++i) {
            float4 v = p4[i];
            pr[4*i+0] = v.x; pr[4*i+1] = v.y; pr[4*i+2] = v.z; pr[4*i+3] = v.w;
        }
        const float pnn = pn[pt];
        while (mask) {
            const int i = __ffs(mask) - 1;
            mask &= mask - 1;
            // re-load key by runtime index (L1-hot line) instead of indexing ks[]
            const unsigned m = candk[((size_t)q * N_ + pt) * 16 + i] & 0xFFFu;
            const float* cm = c + (size_t)m * D_;
            float a0 = 0.f, a1 = 0.f, a2 = 0.f, a3 = 0.f;
#pragma unroll
            for (int k = 0; k < D_; k += 4) {   // round-2 canonical arithmetic
                a0 = fmaf(pr[k+0], cm[k+0], a0);
                a1 = fmaf(pr[k+1], cm[k+1], a1);
                a2 = fmaf(pr[k+2], cm[k+2], a2);
                a3 = fmaf(pr[k+3], cm[k+3], a3);
            }
            const float dot  = (a0 + a1) + (a2 + a3);
            const float dist = fmaf(-2.f, dot, pnn + c_sq[m]);
            const unsigned long long key = pack_dl(dist, m);
            best = key < best ? key : best;
        }
    }
    // merge across the point's 4 lanes; min-key lane always evaluated >=1 candidate
    unsigned long long o1 = __shfl_xor(best, 1); best = o1 < best ? o1 : best;
    unsigned long long o2 = __shfl_xor(best, 2); best = o2 < best ? o2 : best;
    if (q == 0) {
        out[pt]      = __uint_as_float((unsigned)(best >> 32));
        out[N_ + pt] = (float)(unsigned)(best & 0xffffffffu);
    }
}

// ---------------- fallback: f32 VALU path ------------------------------------------
constexpr int FCH = 8;
constexpr int FMC = M_ / FCH;

__global__ __launch_bounds__(256) void pwd_chunk(
        const float* __restrict__ p, const float* __restrict__ pn,
        const float* __restrict__ c, const float* __restrict__ c_sq,
        unsigned long long* __restrict__ ws) {
    const int n = blockIdx.x * 256 + threadIdx.x;
    const int mbase = blockIdx.y * FMC;
    float prr[D_];
    const float4* p4 = reinterpret_cast<const float4*>(p + (size_t)n * D_);
#pragma unroll
    for (int i = 0; i < D_ / 4; ++i) {
        float4 v = p4[i];
        prr[4*i+0] = v.x; prr[4*i+1] = v.y; prr[4*i+2] = v.z; prr[4*i+3] = v.w;
    }
    const float pnn = pn[n];
    float bestD = INFINITY;
    int   bestM = mbase;
#pragma unroll 2
    for (int mi = 0; mi < FMC; ++mi) {
        const int m = mbase + mi;
        const float* cm = c + (size_t)m * D_;
        float a0 = 0.f, a1 = 0.f, a2 = 0.f, a3 = 0.f;
#pragma unroll
        for (int k = 0; k < D_; k += 4) {
            a0 = fmaf(prr[k+0], cm[k+0], a0);
            a1 = fmaf(prr[k+1], cm[k+1], a1);
            a2 = fmaf(prr[k+2], cm[k+2], a2);
            a3 = fmaf(prr[k+3], cm[k+3], a3);
        }
        const float dot  = (a0 + a1) + (a2 + a3);
        const float dist = fmaf(-2.f, dot, pnn + c_sq[m]);
        if (dist < bestD) { bestD = dist; bestM = m; }
    }
    atomicMin(&ws[n], pack_dl(bestD, (unsigned)bestM));
}

__global__ __launch_bounds__(256) void pwd_out(
        const unsigned long long* __restrict__ results, float* __restrict__ out) {
    const int n = blockIdx.x * 256 + threadIdx.x;
    const unsigned long long v = results[n];
    out[n]      = __uint_as_float((unsigned)(v >> 32));
    out[N_ + n] = (float)(unsigned)(v & 0xffffffffu);
}

extern "C" void kernel_launch(void* const* d_in, const int* in_sizes, int n_in,
                              void* d_out, int out_size, void* d_ws, size_t ws_size,
                              hipStream_t stream) {
    const float* p    = (const float*)d_in[0];
    const float* pn   = (const float*)d_in[1];
    const float* c    = (const float*)d_in[2];
    const float* c_sq = (const float*)d_in[3];
    float* out = (float*)d_out;

    char* ws = (char*)d_ws;
    const size_t off_chi  = 0;                                   // 512 KB
    const size_t off_nhc  = (size_t)M_ * D_ * 2;                 // +16 KB
    const size_t off_cand = off_nhc + (size_t)M_ * 4;
    const size_t need     = off_cand + (size_t)Q_ * N_ * 16 * 4; // +16 MB

    if (ws_size >= need) {
        unsigned short* ChiT  = (unsigned short*)(ws + off_chi);
        float*          nhcsq = (float*)(ws + off_nhc);
        unsigned*       candk = (unsigned*)(ws + off_cand);

        constexpr int PREP_T = M_ * D_ / 8 + M_;
        pwd_prep<<<(PREP_T + 255) / 256, 256, 0, stream>>>(c, c_sq, ChiT, nhcsq);
        dim3 sgrid(N_ / 128, Q_);
        pwd_scan<<<sgrid, 256, 0, stream>>>(p, pn, ChiT, nhcsq, candk);
        pwd_exact<<<(N_ * 4) / 256, 256, 0, stream>>>(p, pn, c, c_sq, candk, out);
    } else if (ws_size >= (size_t)N_ * 8) {
        unsigned long long* results = (unsigned long long*)ws;
        hipMemsetAsync(ws, 0xFF, (size_t)N_ * 8, stream);
        dim3 grid(N_ / 256, FCH);
        pwd_chunk<<<grid, 256, 0, stream>>>(p, pn, c, c_sq, results);
        pwd_out<<<N_ / 256, 256, 0, stream>>>(results, out);
    }
}